// Round 1
// baseline (296.433 us; speedup 1.0000x reference)
//
#include <hip/hip_runtime.h>
#include <hip/hip_bf16.h>

// GroupContrast loss, restructured to avoid materializing the 8192x8192 logits.
// Per-row reductions: A = sum_pos L, P = sum_pos exp(L), Q = sum_neg exp(L)
// with L_ij = 100*(f_i . f_j) - 100 (shift-invariant; diag is the row max).
// mlpp_i = A/pc - log(pc) - log(P/pc + Q/nc);  loss = -T * mean_valid(mlpp).

#define N_ROWS 8192
#define D_PAD 320          // 300 padded to 10*32 for K-loop of 16x16x32 MFMA
#define NG 100
#define TEMP 0.01f
#define NSPLIT 4
#define JCHUNK (N_ROWS / NSPLIT)

typedef short short8v __attribute__((ext_vector_type(8)));
typedef float float4v __attribute__((ext_vector_type(4)));

// ---------------- fp32 tiled GEMM: C = act(A @ B + bias) ----------------
// A: M x 300 row-major, B: 300 x 300 row-major, C: M x 300. BK=20 (300=15*20).
__global__ __launch_bounds__(256) void gemm_kernel(
    const float* __restrict__ A, const float* __restrict__ B,
    const float* __restrict__ bias, float* __restrict__ C, int relu)
{
  __shared__ float As[20][64];   // k-major
  __shared__ float Bs[20][64];
  int tid = threadIdx.x;
  int tx = tid & 15, ty = tid >> 4;
  int n0 = blockIdx.x * 64;
  int m0 = blockIdx.y * 64;
  float acc[4][4] = {};
  for (int kt = 0; kt < 15; ++kt) {
    int k0 = kt * 20;
    for (int t = 0; t < 5; ++t) {           // 1280 elems each tile, 5/thread
      int e = tid + t * 256;
      int r = e / 20, c = e % 20;
      As[c][r] = A[(size_t)(m0 + r) * 300 + (k0 + c)];
      int r2 = e >> 6, c2 = e & 63;
      int col = n0 + c2;
      Bs[r2][c2] = (col < 300) ? B[(size_t)(k0 + r2) * 300 + col] : 0.0f;
    }
    __syncthreads();
    for (int k = 0; k < 20; ++k) {
      float4 a = *(const float4*)&As[k][ty * 4];
      float4 b = *(const float4*)&Bs[k][tx * 4];
      float av[4] = {a.x, a.y, a.z, a.w};
      float bv[4] = {b.x, b.y, b.z, b.w};
      for (int i = 0; i < 4; ++i)
        for (int j = 0; j < 4; ++j)
          acc[i][j] = fmaf(av[i], bv[j], acc[i][j]);
    }
    __syncthreads();
  }
  for (int i = 0; i < 4; ++i) {
    int row = m0 + ty * 4 + i;
    for (int j = 0; j < 4; ++j) {
      int col = n0 + tx * 4 + j;
      if (col < 300) {
        float v = acc[i][j] + bias[col];
        if (relu) v = fmaxf(v, 0.0f);
        C[(size_t)row * 300 + col] = v;
      }
    }
  }
}

// ------------- row L2-normalize -> bf16, padded to D_PAD cols -------------
__global__ __launch_bounds__(256) void rownorm_kernel(
    const float* __restrict__ H, __hip_bfloat16* __restrict__ F)
{
  int wave = threadIdx.x >> 6, lane = threadIdx.x & 63;
  int row = blockIdx.x * 4 + wave;
  const float* h = H + (size_t)row * 300;
  float v[5];
  float ss = 0.f;
  for (int t = 0; t < 5; ++t) {
    int c = lane + t * 64;
    v[t] = (c < 300) ? h[c] : 0.f;
    ss += v[t] * v[t];
  }
  for (int m = 1; m < 64; m <<= 1) ss += __shfl_xor(ss, m, 64);
  float inv = 1.0f / sqrtf(ss);
  for (int t = 0; t < 5; ++t) {
    int c = lane + t * 64;
    F[(size_t)row * D_PAD + c] = __float2bfloat16(v[t] * inv);  // pad cols = 0
  }
}

// ---------------- label histogram (labels in 1..NG) ----------------
__global__ __launch_bounds__(256) void hist_kernel(
    const int* __restrict__ labels, int* __restrict__ counts)
{
  __shared__ int hc[NG + 1];
  int tid = threadIdx.x;
  if (tid <= NG) hc[tid] = 0;
  __syncthreads();
  for (int i = tid; i < N_ROWS; i += 256) atomicAdd(&hc[labels[i]], 1);
  __syncthreads();
  if (tid <= NG) counts[tid] = hc[tid];
}

// ---------------- pairwise bf16 MFMA pass ----------------
// Block: 64 i-rows x one j-split of 2048. 4 waves; wave w owns i-sub rows
// [w*16, w*16+16). A-frags preloaded to registers (full K=320).
// j-tile of 64 rows staged in LDS with padded stride 328 (bank-uniform b128).
__global__ __launch_bounds__(256) void pairwise_kernel(
    const __hip_bfloat16* __restrict__ Fb, const int* __restrict__ labels,
    float* __restrict__ partP, float* __restrict__ partQ,
    float* __restrict__ partA)
{
  __shared__ __align__(16) short Bs[64 * 328];
  __shared__ int labj_s[64];
  const short* Fs = (const short*)Fb;
  int tid = threadIdx.x;
  int lane = tid & 63, wave = tid >> 6;
  int g = lane >> 4, lc = lane & 15;
  int i0 = blockIdx.x * 64;
  int split = blockIdx.y;
  int jstart = split * JCHUNK;

  // A fragments: lane holds A[m=lc][k=g*8 + t] per 32-wide K step
  short8v afr[10];
  {
    const short* ap = Fs + (size_t)(i0 + wave * 16 + lc) * D_PAD + g * 8;
    for (int kk = 0; kk < 10; ++kk)
      afr[kk] = *(const short8v*)(ap + kk * 32);
  }
  int ibase = i0 + wave * 16 + g * 4;   // C-layout rows owned by this lane
  int labi[4];
  for (int r = 0; r < 4; ++r) labi[r] = labels[ibase + r];
  float sA[4] = {}, sP[4] = {}, sQ[4] = {};

  for (int jt = 0; jt < JCHUNK / 64; ++jt) {
    int jb = jstart + jt * 64;
    __syncthreads();
    {
      // flat-ish copy of F[jb..jb+63][0..319] into stride-328 LDS tile
      const int4* src = (const int4*)Fs;   // 8 shorts per int4; 40 per row
      int4* dst = (int4*)Bs;               // 41 int4 per padded row
      for (int t = 0; t < 10; ++t) {
        int e = tid + t * 256;
        int r = e / 40, q = e % 40;
        dst[r * 41 + q] = src[(size_t)(jb + r) * 40 + q];
      }
      if (tid < 64) labj_s[tid] = labels[jb + tid];
    }
    __syncthreads();
    bool dtile = (jb == i0);
    for (int js = 0; js < 4; ++js) {
      float4v acc = {0.f, 0.f, 0.f, 0.f};
      const short* bp = Bs + (js * 16 + lc) * 328 + g * 8;
      for (int kk = 0; kk < 10; ++kk) {
        short8v bf = *(const short8v*)(bp + kk * 32);
        acc = __builtin_amdgcn_mfma_f32_16x16x32_bf16(afr[kk], bf, acc, 0, 0, 0);
      }
      int jloc = js * 16 + lc;
      int lj = labj_s[jloc];
      for (int r = 0; r < 4; ++r) {
        float L = fmaf(acc[r], 100.0f, -100.0f);
        float e = __expf(L);
        bool pos = (labi[r] == lj);
        bool dg = dtile && (jloc == (wave * 16 + g * 4 + r));
        if (pos && !dg) { sA[r] += L; sP[r] += e; }
        if (!pos) sQ[r] += e;
      }
    }
  }
  // reduce across the 16 lanes (low 4 bits) that share the same rows
  for (int m = 1; m < 16; m <<= 1)
    for (int r = 0; r < 4; ++r) {
      sA[r] += __shfl_xor(sA[r], m, 64);
      sP[r] += __shfl_xor(sP[r], m, 64);
      sQ[r] += __shfl_xor(sQ[r], m, 64);
    }
  if (lc == 0) {
    for (int r = 0; r < 4; ++r) {
      int i = ibase + r;
      partP[split * N_ROWS + i] = sP[r];
      partQ[split * N_ROWS + i] = sQ[r];
      partA[split * N_ROWS + i] = sA[r];
    }
  }
}

// ---------------- final per-row combine + loss reduce ----------------
__global__ __launch_bounds__(256) void final_kernel(
    const float* __restrict__ partP, const float* __restrict__ partQ,
    const float* __restrict__ partA, const int* __restrict__ counts,
    const int* __restrict__ labels, float* __restrict__ out)
{
  int tid = threadIdx.x;
  float sumM = 0.f, sumV = 0.f;
  for (int i = tid; i < N_ROWS; i += 256) {
    float P = 0.f, Q = 0.f, A = 0.f;
    for (int s = 0; s < NSPLIT; ++s) {
      P += partP[s * N_ROWS + i];
      Q += partQ[s * N_ROWS + i];
      A += partA[s * N_ROWS + i];
    }
    int pc = counts[labels[i]] - 1;
    if (pc > 0) {
      float pcf = (float)pc;
      float ncf = (float)(N_ROWS - 1 - pc);
      float Z = P / pcf + Q / ncf;
      sumM += A / pcf - logf(pcf) - logf(Z);
      sumV += 1.f;
    }
  }
  __shared__ float rm[256], rv[256];
  rm[tid] = sumM; rv[tid] = sumV;
  __syncthreads();
  for (int s = 128; s > 0; s >>= 1) {
    if (tid < s) { rm[tid] += rm[tid + s]; rv[tid] += rv[tid + s]; }
    __syncthreads();
  }
  if (tid == 0) out[0] = (rv[0] > 0.f) ? (-TEMP * rm[0] / rv[0]) : 0.f;
}

extern "C" void kernel_launch(void* const* d_in, const int* in_sizes, int n_in,
                              void* d_out, int out_size, void* d_ws, size_t ws_size,
                              hipStream_t stream)
{
  const float* x  = (const float*)d_in[0];
  const float* W1 = (const float*)d_in[1];
  const float* b1 = (const float*)d_in[2];
  const float* W2 = (const float*)d_in[3];
  const float* b2 = (const float*)d_in[4];
  const int* labels = (const int*)d_in[5];

  char* ws = (char*)d_ws;
  float* h1 = (float*)(ws);                         // 8192*300*4 = 9,830,400
  float* h2 = (float*)(ws + 9830400);               // 9,830,400
  __hip_bfloat16* fb = (__hip_bfloat16*)(ws + 19660800);  // 8192*320*2 = 5,242,880
  int* counts = (int*)(ws + 24903680);              // 101 ints (padded to 512)
  float* partP = (float*)(ws + 24904192);           // 4*8192 floats each
  float* partQ = partP + NSPLIT * N_ROWS;
  float* partA = partQ + NSPLIT * N_ROWS;

  gemm_kernel<<<dim3(5, 128), 256, 0, stream>>>(x, W1, b1, h1, 1);
  gemm_kernel<<<dim3(5, 128), 256, 0, stream>>>(h1, W2, b2, h2, 0);
  rownorm_kernel<<<2048, 256, 0, stream>>>(h2, fb);
  hist_kernel<<<1, 256, 0, stream>>>(labels, counts);
  pairwise_kernel<<<dim3(128, NSPLIT), 256, 0, stream>>>(fb, labels, partP, partQ, partA);
  final_kernel<<<1, 256, 0, stream>>>(partP, partQ, partA, counts, labels, (float*)d_out);
}

// Round 2
// 236.275 us; speedup vs baseline: 1.2546x; 1.2546x over previous
//
#include <hip/hip_runtime.h>
#include <hip/hip_bf16.h>

// GroupContrast loss. Per-row reductions instead of the 8192x8192 logits:
//   sE = sum_j exp(L), sP = sum_pos exp(L), sAcc = sum_pos acc   (diag-corrected)
//   L_ij = 100*acc_ij - 100, acc = f_i.f_j (bf16 MFMA).
//   Q = sE - sP (diag cancels), P = sP, A = 100*sAcc - 100*pc.
//   mlpp_i = 100*sAcc/pc - 100 - log(pc) - log(P/pc + Q/nc); loss = -T*mean_valid.
// MLP runs on bf16 MFMA too (W pre-transposed to n-major, padded K/N->320).

#define N_ROWS 8192
#define D_PAD 320
#define NG 100
#define TEMP 0.01f
#define NSPLIT 16
#define JCHUNK (N_ROWS / NSPLIT)   // 512

typedef short short8v __attribute__((ext_vector_type(8)));
typedef float float4v __attribute__((ext_vector_type(4)));

// ---------- cast x (8192x300 f32) -> bf16 [8192][320], zero-padded ----------
__global__ __launch_bounds__(256) void cast_x_kernel(
    const float* __restrict__ x, __hip_bfloat16* __restrict__ xb)
{
  int idx = blockIdx.x * 256 + threadIdx.x;      // N_ROWS*D_PAD threads
  int m = idx / D_PAD, k = idx - m * D_PAD;
  float v = (k < 300) ? x[(size_t)m * 300 + k] : 0.0f;
  xb[idx] = __float2bfloat16(v);
}

// ---------- cast+transpose W (300x300 f32 row-major) -> Wt bf16 [n=320][k=320] ----------
__global__ __launch_bounds__(256) void cast_w_kernel(
    const float* __restrict__ W, __hip_bfloat16* __restrict__ Wt)
{
  int idx = blockIdx.x * 256 + threadIdx.x;      // D_PAD*D_PAD threads
  int n = idx / D_PAD, k = idx - n * D_PAD;
  float v = (n < 300 && k < 300) ? W[(size_t)k * 300 + n] : 0.0f;
  Wt[idx] = __float2bfloat16(v);
}

// ---------- bf16 MFMA GEMM: C = act(A @ Wt^T + bias) ----------
// A: [M][320] bf16 row-major. Wt: [320 n][320 k] bf16. Block = 64 i-rows x 64 n-cols.
// mode 0: relu, bf16 out (stride 320). mode 1: fp32 out (stride 320).
__global__ __launch_bounds__(256) void mlp_gemm_kernel(
    const __hip_bfloat16* __restrict__ Ab, const __hip_bfloat16* __restrict__ Wt,
    const float* __restrict__ bias, void* __restrict__ Cout, int mode)
{
  __shared__ __align__(16) short Bs[64 * 328];
  const short* As = (const short*)Ab;
  const short* Ws = (const short*)Wt;
  int tid = threadIdx.x;
  int lane = tid & 63, wave = tid >> 6;
  int g = lane >> 4, lc = lane & 15;
  int i0 = blockIdx.x * 64;
  int n0 = blockIdx.y * 64;

  {  // stage Wt rows n0..n0+63 (40 int4 each) into stride-41 int4 LDS rows
    const int4* src = (const int4*)Ws;
    int4* dst = (int4*)Bs;
    for (int t = 0; t < 10; ++t) {
      int e = tid + t * 256;
      int r = e / 40, q = e - r * 40;
      dst[r * 41 + q] = src[(size_t)(n0 + r) * 40 + q];
    }
  }
  short8v afr[10];
  {
    const short* ap = As + (size_t)(i0 + wave * 16 + lc) * D_PAD + g * 8;
    for (int kk = 0; kk < 10; ++kk) afr[kk] = *(const short8v*)(ap + kk * 32);
  }
  __syncthreads();
  for (int js = 0; js < 4; ++js) {
    float4v acc = {0.f, 0.f, 0.f, 0.f};
    const short* bp = Bs + (js * 16 + lc) * 328 + g * 8;
    for (int kk = 0; kk < 10; ++kk) {
      short8v bf = *(const short8v*)(bp + kk * 32);
      acc = __builtin_amdgcn_mfma_f32_16x16x32_bf16(afr[kk], bf, acc, 0, 0, 0);
    }
    int n = n0 + js * 16 + lc;
    float bv = (n < 300) ? bias[n] : 0.0f;
    for (int r = 0; r < 4; ++r) {
      int m = i0 + wave * 16 + g * 4 + r;
      float v = acc[r] + bv;
      if (mode == 0) {
        v = fmaxf(v, 0.0f);
        ((__hip_bfloat16*)Cout)[(size_t)m * D_PAD + n] = __float2bfloat16(v);
      } else {
        ((float*)Cout)[(size_t)m * D_PAD + n] = v;
      }
    }
  }
}

// ---------- row L2-normalize (fp32 [8192][320], pads=0) -> bf16 [8192][320] ----------
__global__ __launch_bounds__(256) void rownorm_kernel(
    const float* __restrict__ H, __hip_bfloat16* __restrict__ F)
{
  int wave = threadIdx.x >> 6, lane = threadIdx.x & 63;
  int row = blockIdx.x * 4 + wave;
  const float* h = H + (size_t)row * D_PAD;
  float v[5];
  float ss = 0.f;
  for (int t = 0; t < 5; ++t) { v[t] = h[lane + t * 64]; ss += v[t] * v[t]; }
  for (int m = 1; m < 64; m <<= 1) ss += __shfl_xor(ss, m, 64);
  float inv = rsqrtf(ss);
  for (int t = 0; t < 5; ++t)
    F[(size_t)row * D_PAD + lane + t * 64] = __float2bfloat16(v[t] * inv);
}

// ---------- label histogram (labels in 1..NG) ----------
__global__ __launch_bounds__(256) void hist_kernel(
    const int* __restrict__ labels, int* __restrict__ counts)
{
  __shared__ int hc[NG + 1];
  int tid = threadIdx.x;
  if (tid <= NG) hc[tid] = 0;
  __syncthreads();
  for (int i = tid; i < N_ROWS; i += 256) atomicAdd(&hc[labels[i]], 1);
  __syncthreads();
  if (tid <= NG) counts[tid] = hc[tid];
}

// ---------- pairwise bf16 MFMA pass ----------
// Block: 128 i-rows (4 waves x 2 strips of 16) x one 512-col j-split.
// Each LDS B-fragment is reused by 2 MFMAs (strip0/strip1) -> halved LDS traffic.
__global__ __launch_bounds__(256, 2) void pairwise_kernel(
    const __hip_bfloat16* __restrict__ Fb, const int* __restrict__ labels,
    float* __restrict__ partP, float* __restrict__ partQ,
    float* __restrict__ partA)
{
  __shared__ __align__(16) short Bs[64 * 328];
  __shared__ int labj_s[64];
  const short* Fs = (const short*)Fb;
  int tid = threadIdx.x;
  int lane = tid & 63, wave = tid >> 6;
  int g = lane >> 4, lc = lane & 15;
  int i0 = blockIdx.x * 128;
  int split = blockIdx.y;
  int jstart = split * JCHUNK;

  short8v afr[2][10];
  int labi[2][4];
  for (int s = 0; s < 2; ++s) {
    const short* ap = Fs + (size_t)(i0 + s * 64 + wave * 16 + lc) * D_PAD + g * 8;
    for (int kk = 0; kk < 10; ++kk) afr[s][kk] = *(const short8v*)(ap + kk * 32);
    int ib = i0 + s * 64 + wave * 16 + g * 4;
    for (int r = 0; r < 4; ++r) labi[s][r] = labels[ib + r];
  }
  float sE[2][4] = {}, sP[2][4] = {}, sA[2][4] = {};

  for (int jt = 0; jt < JCHUNK / 64; ++jt) {
    int jb = jstart + jt * 64;
    __syncthreads();
    {
      const int4* src = (const int4*)Fs;
      int4* dst = (int4*)Bs;
      for (int t = 0; t < 10; ++t) {
        int e = tid + t * 256;
        int r = e / 40, q = e - r * 40;
        dst[r * 41 + q] = src[(size_t)(jb + r) * 40 + q];
      }
      if (tid < 64) labj_s[tid] = labels[jb + tid];
    }
    __syncthreads();
    for (int js = 0; js < 4; ++js) {
      float4v acc0 = {0.f, 0.f, 0.f, 0.f}, acc1 = {0.f, 0.f, 0.f, 0.f};
      const short* bp = Bs + (js * 16 + lc) * 328 + g * 8;
      for (int kk = 0; kk < 10; ++kk) {
        short8v bf = *(const short8v*)(bp + kk * 32);
        acc0 = __builtin_amdgcn_mfma_f32_16x16x32_bf16(afr[0][kk], bf, acc0, 0, 0, 0);
        acc1 = __builtin_amdgcn_mfma_f32_16x16x32_bf16(afr[1][kk], bf, acc1, 0, 0, 0);
      }
      int jloc = js * 16 + lc;
      int lj = labj_s[jloc];
      for (int s = 0; s < 2; ++s) {
        bool dtile = (jb == i0 + s * 64) && (js == wave);
        float4v acc = s ? acc1 : acc0;
        for (int r = 0; r < 4; ++r) {
          float a = acc[r];
          float e = __expf(fmaf(a, 100.0f, -100.0f));
          bool pos = (labi[s][r] == lj);
          sE[s][r] += e;
          sP[s][r] += pos ? e : 0.0f;
          sA[s][r] += pos ? a : 0.0f;
          if (dtile && lc == g * 4 + r) {   // diagonal: remove from all three
            sE[s][r] -= e; sP[s][r] -= e; sA[s][r] -= a;
          }
        }
      }
    }
  }
  for (int m = 1; m < 16; m <<= 1)
    for (int s = 0; s < 2; ++s)
      for (int r = 0; r < 4; ++r) {
        sE[s][r] += __shfl_xor(sE[s][r], m, 64);
        sP[s][r] += __shfl_xor(sP[s][r], m, 64);
        sA[s][r] += __shfl_xor(sA[s][r], m, 64);
      }
  if (lc == 0) {
    for (int s = 0; s < 2; ++s)
      for (int r = 0; r < 4; ++r) {
        int i = i0 + s * 64 + wave * 16 + g * 4 + r;
        partP[split * N_ROWS + i] = sP[s][r];
        partQ[split * N_ROWS + i] = sE[s][r] - sP[s][r];
        partA[split * N_ROWS + i] = sA[s][r];
      }
  }
}

// ---------- final per-row combine + loss reduce ----------
__global__ __launch_bounds__(256) void final_kernel(
    const float* __restrict__ partP, const float* __restrict__ partQ,
    const float* __restrict__ partA, const int* __restrict__ counts,
    const int* __restrict__ labels, float* __restrict__ out)
{
  int tid = threadIdx.x;
  float sumM = 0.f, sumV = 0.f;
  for (int i = tid; i < N_ROWS; i += 256) {
    float P = 0.f, Q = 0.f, A = 0.f;
    for (int s = 0; s < NSPLIT; ++s) {
      P += partP[s * N_ROWS + i];
      Q += partQ[s * N_ROWS + i];
      A += partA[s * N_ROWS + i];
    }
    int pc = counts[labels[i]] - 1;
    if (pc > 0) {
      float pcf = (float)pc;
      float ncf = (float)(N_ROWS - 1 - pc);
      float Z = P / pcf + Q / ncf;
      sumM += 100.0f * A / pcf - 100.0f - logf(pcf) - logf(Z);
      sumV += 1.f;
    }
  }
  __shared__ float rm[256], rv[256];
  rm[tid] = sumM; rv[tid] = sumV;
  __syncthreads();
  for (int s = 128; s > 0; s >>= 1) {
    if (tid < s) { rm[tid] += rm[tid + s]; rv[tid] += rv[tid + s]; }
    __syncthreads();
  }
  if (tid == 0) out[0] = (rv[0] > 0.f) ? (-TEMP * rm[0] / rv[0]) : 0.f;
}

extern "C" void kernel_launch(void* const* d_in, const int* in_sizes, int n_in,
                              void* d_out, int out_size, void* d_ws, size_t ws_size,
                              hipStream_t stream)
{
  const float* x  = (const float*)d_in[0];
  const float* W1 = (const float*)d_in[1];
  const float* b1 = (const float*)d_in[2];
  const float* W2 = (const float*)d_in[3];
  const float* b2 = (const float*)d_in[4];
  const int* labels = (const int*)d_in[5];

  char* ws = (char*)d_ws;
  __hip_bfloat16* xb  = (__hip_bfloat16*)(ws);              // 5,242,880 B
  __hip_bfloat16* fb  = (__hip_bfloat16*)(ws);              // reuses xb (dead after gemm1)
  __hip_bfloat16* h1  = (__hip_bfloat16*)(ws + 5242880);    // 5,242,880 B
  float*          h2  = (float*)(ws + 10485760);            // 10,485,760 B
  __hip_bfloat16* w1t = (__hip_bfloat16*)(ws + 20971520);   // 204,800 B
  __hip_bfloat16* w2t = (__hip_bfloat16*)(ws + 21176320);   // 204,800 B
  int*         counts = (int*)(ws + 21381120);              // 512 B
  float*        partP = (float*)(ws + 21381632);            // 524,288 B each
  float*        partQ = partP + NSPLIT * N_ROWS;
  float*        partA = partQ + NSPLIT * N_ROWS;

  cast_x_kernel<<<N_ROWS * D_PAD / 256, 256, 0, stream>>>(x, xb);
  cast_w_kernel<<<D_PAD * D_PAD / 256, 256, 0, stream>>>(W1, w1t);
  cast_w_kernel<<<D_PAD * D_PAD / 256, 256, 0, stream>>>(W2, w2t);
  hist_kernel<<<1, 256, 0, stream>>>(labels, counts);
  mlp_gemm_kernel<<<dim3(N_ROWS / 64, 5), 256, 0, stream>>>(xb, w1t, b1, h1, 0);
  mlp_gemm_kernel<<<dim3(N_ROWS / 64, 5), 256, 0, stream>>>(h1, w2t, b2, h2, 1);
  rownorm_kernel<<<N_ROWS / 4, 256, 0, stream>>>(h2, fb);
  pairwise_kernel<<<dim3(N_ROWS / 128, NSPLIT), 256, 0, stream>>>(fb, labels, partP, partQ, partA);
  final_kernel<<<1, 256, 0, stream>>>(partP, partQ, partA, counts, labels, (float*)d_out);
}